// Round 2
// baseline (158.917 us; speedup 1.0000x reference)
//
#include <hip/hip_runtime.h>
#include <hip/hip_bf16.h>
#include <stdint.h>

// If validation fails, flip this to 0: selects JAX's legacy (non-partitionable)
// threefry split/random_bits layout instead of jax_threefry_partitionable=True.
#define THREEFRY_PARTITIONABLE 1

namespace {

constexpr int N = 4096;      // input length
constexpr int K = 44;        // int(sqrt(2*MAX_PAIRS)) = int(sqrt(2000)) = 44
constexpr int NTHREADS = 1024;
constexpr float MARGIN = 0.01f;

struct U2 { uint32_t x, y; };

// Threefry-2x32, 20 rounds — matches jax._src.prng.threefry2x32 reference.
__device__ inline U2 tf2x32(uint32_t k0, uint32_t k1, uint32_t x0, uint32_t x1) {
  const uint32_t ks0 = k0, ks1 = k1, ks2 = k0 ^ k1 ^ 0x1BD11BDAu;
  uint32_t ks[3] = {ks0, ks1, ks2};
  x0 += ks0; x1 += ks1;
  const int rot0[4] = {13, 15, 26, 6};
  const int rot1[4] = {17, 29, 16, 24};
#pragma unroll
  for (int i = 0; i < 5; ++i) {
    const int* r = (i & 1) ? rot1 : rot0;
#pragma unroll
    for (int j = 0; j < 4; ++j) {
      x0 += x1;
      x1 = (x1 << r[j]) | (x1 >> (32 - r[j]));
      x1 ^= x0;
    }
    x0 += ks[(i + 1) % 3];
    x1 += ks[(i + 2) % 3] + (uint32_t)(i + 1);
  }
  return {x0, x1};
}

#if THREEFRY_PARTITIONABLE
// split(key): subkeys are whole threefry outputs of 64-bit counters 0 and 1.
__device__ inline void splitk(U2 key, U2& nk, U2& sk) {
  nk = tf2x32(key.x, key.y, 0u, 0u);
  sk = tf2x32(key.x, key.y, 0u, 1u);
}
// random_bits(sub, 32, (N,))[i] = y0 ^ y1 of counter (hi=0, lo=i)
__device__ inline uint32_t sortkey(U2 sub, uint32_t i) {
  U2 r = tf2x32(sub.x, sub.y, 0u, i);
  return r.x ^ r.y;
}
#else
// legacy split: counts=[0,1,2,3] halved -> pairs (0,2),(1,3); out = concat(y0s, y1s)
__device__ inline void splitk(U2 key, U2& nk, U2& sk) {
  U2 a = tf2x32(key.x, key.y, 0u, 2u);
  U2 b = tf2x32(key.x, key.y, 1u, 3u);
  nk = {a.x, b.x};
  sk = {a.y, b.y};
}
// legacy random_bits: counts=iota(N) halved -> pairs (i, i+N/2); out = concat(y0s, y1s)
__device__ inline uint32_t sortkey(U2 sub, uint32_t i) {
  if (i < N / 2) return tf2x32(sub.x, sub.y, i, i + N / 2).x;
  return tf2x32(sub.x, sub.y, i - N / 2, i).y;
}
#endif

} // namespace

__global__ __launch_bounds__(NTHREADS)
void RankingLoss_29540785062186_kernel(const float* __restrict__ pred,
                                       const float* __restrict__ targ,
                                       float* __restrict__ out) {
  __shared__ unsigned long long skeys[N];  // (sort_key << 32) | position  (stable sort)
  __shared__ uint32_t svals[N];            // permutation being shuffled
  __shared__ float sp[K], st[K];
  __shared__ float red_sum[NTHREADS / 64];
  __shared__ float red_cnt[NTHREADS / 64];

  const int tid = threadIdx.x;

  // ---- key chain: key(42) = (hi=0, lo=42); two shuffle rounds ----
  U2 key = {0u, 42u};
  U2 key1, sub1, key2, sub2;
  splitk(key, key1, sub1);
  splitk(key1, key2, sub2);

  // ---- round 1: keys + identity values ----
  for (int i = tid; i < N; i += NTHREADS) {
    uint32_t sk = sortkey(sub1, (uint32_t)i);
    skeys[i] = ((unsigned long long)sk << 32) | (uint32_t)i;
    svals[i] = (uint32_t)i;
  }

  // ---- bitonic sort (ascending, composite keys unique => matches stable sort) ----
#pragma unroll 1
  for (int round = 0; round < 2; ++round) {
    for (int size = 2; size <= N; size <<= 1) {
      for (int stride = size >> 1; stride > 0; stride >>= 1) {
        __syncthreads();
        for (int t = tid; t < N / 2; t += NTHREADS) {
          int lo = (t & (stride - 1)) | ((t & ~(stride - 1)) << 1);
          int hi = lo + stride;
          bool desc = (lo & size) != 0;
          unsigned long long a = skeys[lo], b = skeys[hi];
          if ((a > b) != desc) {
            skeys[lo] = b; skeys[hi] = a;
            uint32_t va = svals[lo]; svals[lo] = svals[hi]; svals[hi] = va;
          }
        }
      }
    }
    __syncthreads();
    if (round == 0) {
      // ---- round 2 keys attach to current positions; values carry over ----
      for (int i = tid; i < N; i += NTHREADS) {
        uint32_t sk = sortkey(sub2, (uint32_t)i);
        skeys[i] = ((unsigned long long)sk << 32) | (uint32_t)i;
      }
    }
  }

  // ---- gather sampled predictions/targets: idx = svals[0:K] ----
  if (tid < K) {
    uint32_t idx = svals[tid];
    sp[tid] = pred[idx];
    st[tid] = targ[idx];
  }
  __syncthreads();

  // ---- pairwise margin ranking loss over upper triangle ----
  float lsum = 0.f, lcnt = 0.f;
  for (int q = tid; q < K * K; q += NTHREADS) {
    int i = q / K, j = q % K;
    if (j > i) {
      float ta = st[i], tb = st[j], pa = sp[i], pb = sp[j];
      bool c1 = ta > tb + MARGIN;
      bool c2 = tb > ta + MARGIN;
      float term = c1 ? fmaxf(pb - pa + MARGIN, 0.f)
                      : (c2 ? fmaxf(pa - pb + MARGIN, 0.f) : 0.f);
      lsum += term;
      lcnt += (c1 || c2) ? 1.f : 0.f;
    }
  }
  // wave reduce (64 lanes)
#pragma unroll
  for (int off = 32; off > 0; off >>= 1) {
    lsum += __shfl_down(lsum, off);
    lcnt += __shfl_down(lcnt, off);
  }
  const int wave = tid >> 6, lane = tid & 63;
  if (lane == 0) { red_sum[wave] = lsum; red_cnt[wave] = lcnt; }
  __syncthreads();
  if (tid == 0) {
    float s = 0.f, c = 0.f;
#pragma unroll
    for (int w = 0; w < NTHREADS / 64; ++w) { s += red_sum[w]; c += red_cnt[w]; }
    out[0] = (c > 0.f) ? (s / c) : 0.f;
  }
}

extern "C" void kernel_launch(void* const* d_in, const int* in_sizes, int n_in,
                              void* d_out, int out_size, void* d_ws, size_t ws_size,
                              hipStream_t stream) {
  const float* pred = (const float*)d_in[0];
  const float* targ = (const float*)d_in[1];
  float* out = (float*)d_out;
  hipLaunchKernelGGL(RankingLoss_29540785062186_kernel, dim3(1), dim3(NTHREADS), 0, stream,
                     pred, targ, out);
}

// Round 3
// 67.307 us; speedup vs baseline: 2.3611x; 2.3611x over previous
//
#include <hip/hip_runtime.h>
#include <hip/hip_bf16.h>
#include <stdint.h>

namespace {

constexpr int N = 4096;      // input length
constexpr int K = 44;        // int(sqrt(2*MAX_PAIRS)) = 44
constexpr float MARGIN = 0.01f;

struct U2 { uint32_t x, y; };

// Threefry-2x32, 20 rounds — constexpr so the key chain folds at compile time.
__host__ __device__ constexpr U2 tf(uint32_t k0, uint32_t k1, uint32_t x0, uint32_t x1) {
  const uint32_t ks0 = k0, ks1 = k1, ks2 = k0 ^ k1 ^ 0x1BD11BDAu;
  uint32_t ks[3] = {ks0, ks1, ks2};
  x0 += ks0; x1 += ks1;
  const int rot0[4] = {13, 15, 26, 6};
  const int rot1[4] = {17, 29, 16, 24};
  for (int i = 0; i < 5; ++i) {
    const int* r = (i & 1) ? rot1 : rot0;
    for (int j = 0; j < 4; ++j) {
      x0 += x1;
      x1 = (x1 << r[j]) | (x1 >> (32 - r[j]));
      x1 ^= x0;
    }
    x0 += ks[(i + 1) % 3];
    x1 += ks[(i + 2) % 3] + (uint32_t)(i + 1);
  }
  return {x0, x1};
}

// jax_threefry_partitionable key chain for key(42):
//   key1, sub1 = split(key);  key2, sub2 = split(key1)
// split: subkey = threefry(key, counter=(0,1)); next key = counter (0,0).
constexpr U2 KEY1 = tf(0u, 42u, 0u, 0u);
constexpr U2 SUB1 = tf(0u, 42u, 0u, 1u);
constexpr U2 SUB2 = tf(KEY1.x, KEY1.y, 0u, 1u);

constexpr int JC = 8;            // j-chunks in rank kernel
constexpr int JLEN = N / JC;     // 512 keys per chunk

} // namespace

// ---- kernel A: compute composite sort keys, zero rank arrays ----
__global__ __launch_bounds__(256)
void RL_keys(uint64_t* __restrict__ keys1, uint64_t* __restrict__ keys2,
             uint32_t* __restrict__ rank1, uint32_t* __restrict__ rank2) {
  const uint32_t i = blockIdx.x * 256 + threadIdx.x;
  U2 a = tf(SUB1.x, SUB1.y, 0u, i);   // random_bits(sub1)[i] = y0^y1
  U2 b = tf(SUB2.x, SUB2.y, 0u, i);
  keys1[i] = ((uint64_t)(a.x ^ a.y) << 32) | i;   // stable-sort composite
  keys2[i] = ((uint64_t)(b.x ^ b.y) << 32) | i;
  rank1[i] = 0u;
  rank2[i] = 0u;
}

// ---- kernel B: rank[i] = #{j : key[j] < key[i]} via chunked partial counts ----
// 256 blocks: pass(2) x i-chunk(16, 256 i's) x j-chunk(8, 512 j's)
__global__ __launch_bounds__(256)
void RL_rank(const uint64_t* __restrict__ keys1, const uint64_t* __restrict__ keys2,
             uint32_t* __restrict__ rank1, uint32_t* __restrict__ rank2) {
  __shared__ uint64_t kj[JLEN];
  const int b = blockIdx.x;
  const int pass = b >> 7;            // 0: round-1 keys, 1: round-2 keys
  const int ic = b & 15;
  const int jc = (b >> 4) & 7;
  const uint64_t* __restrict__ keys = pass ? keys2 : keys1;
  uint32_t* __restrict__ rank = pass ? rank2 : rank1;
  const int tid = threadIdx.x;

  // stage this block's j-chunk into LDS (16B per thread, coalesced)
  ((ulonglong2*)kj)[tid] = ((const ulonglong2*)(keys + jc * JLEN))[tid];
  __syncthreads();

  const int i = ic * 256 + tid;
  const uint64_t ki = keys[i];
  uint32_t cnt = 0;
#pragma unroll 8
  for (int j = 0; j < JLEN; ++j) cnt += (kj[j] < ki) ? 1u : 0u;  // uniform addr -> broadcast
  atomicAdd(&rank[i], cnt);
}

// ---- kernel C: build inverse permutation, select 44 smallest, pair loss ----
__global__ __launch_bounds__(1024)
void RL_final(const uint32_t* __restrict__ rank1, const uint32_t* __restrict__ rank2,
              const float* __restrict__ pred, const float* __restrict__ targ,
              float* __restrict__ out) {
  __shared__ uint32_t inv1[N];     // inv1[p] = element at position p after round-1 sort
  __shared__ uint32_t selpos[K];   // positions with the K smallest round-2 keys, in rank order
  __shared__ float sp[K], st[K];
  __shared__ float red_sum[16], red_cnt[16];
  const int tid = threadIdx.x;

  for (int i = tid; i < N; i += 1024) inv1[rank1[i]] = (uint32_t)i;
  for (int p = tid; p < N; p += 1024) {
    uint32_t r = rank2[p];
    if (r < K) selpos[r] = (uint32_t)p;
  }
  __syncthreads();

  if (tid < K) {
    uint32_t idx = inv1[selpos[tid]];
    sp[tid] = pred[idx];
    st[tid] = targ[idx];
  }
  __syncthreads();

  // pairwise margin ranking loss over upper triangle (identical to validated R2)
  float lsum = 0.f, lcnt = 0.f;
  for (int q = tid; q < K * K; q += 1024) {
    int i = q / K, j = q % K;
    if (j > i) {
      float ta = st[i], tb = st[j], pa = sp[i], pb = sp[j];
      bool c1 = ta > tb + MARGIN;
      bool c2 = tb > ta + MARGIN;
      float term = c1 ? fmaxf(pb - pa + MARGIN, 0.f)
                      : (c2 ? fmaxf(pa - pb + MARGIN, 0.f) : 0.f);
      lsum += term;
      lcnt += (c1 || c2) ? 1.f : 0.f;
    }
  }
#pragma unroll
  for (int off = 32; off > 0; off >>= 1) {
    lsum += __shfl_down(lsum, off);
    lcnt += __shfl_down(lcnt, off);
  }
  const int wave = tid >> 6, lane = tid & 63;
  if (lane == 0) { red_sum[wave] = lsum; red_cnt[wave] = lcnt; }
  __syncthreads();
  if (tid == 0) {
    float s = 0.f, c = 0.f;
#pragma unroll
    for (int w = 0; w < 16; ++w) { s += red_sum[w]; c += red_cnt[w]; }
    out[0] = (c > 0.f) ? (s / c) : 0.f;
  }
}

extern "C" void kernel_launch(void* const* d_in, const int* in_sizes, int n_in,
                              void* d_out, int out_size, void* d_ws, size_t ws_size,
                              hipStream_t stream) {
  const float* pred = (const float*)d_in[0];
  const float* targ = (const float*)d_in[1];
  float* out = (float*)d_out;

  uint8_t* w = (uint8_t*)d_ws;                    // 96 KiB used
  uint64_t* keys1 = (uint64_t*)(w);               // 32 KiB
  uint64_t* keys2 = (uint64_t*)(w + 32 * 1024);   // 32 KiB
  uint32_t* rank1 = (uint32_t*)(w + 64 * 1024);   // 16 KiB
  uint32_t* rank2 = (uint32_t*)(w + 80 * 1024);   // 16 KiB

  hipLaunchKernelGGL(RL_keys, dim3(N / 256), dim3(256), 0, stream, keys1, keys2, rank1, rank2);
  hipLaunchKernelGGL(RL_rank, dim3(256), dim3(256), 0, stream, keys1, keys2, rank1, rank2);
  hipLaunchKernelGGL(RL_final, dim3(1), dim3(1024), 0, stream, rank1, rank2, pred, targ, out);
}